// Round 6
// baseline (610.632 us; speedup 1.0000x reference)
//
#include <hip/hip_runtime.h>
#include <hip/hip_bf16.h>

// Problem constants
#define BB 4
#define LL 2048
#define DM 1024
#define DI 2048          // D_INNER
#define DST 16           // D_STATE
#define DTR 64           // DT_RANK
#define ROWS (BB*LL)     // 8192
#define NC 32            // scan chunks
#define CHUNK (LL/NC)    // 64

using bf16x8 = __attribute__((ext_vector_type(8))) __bf16;
using f32x4  = __attribute__((ext_vector_type(4))) float;

#define AS1 __attribute__((address_space(1)))
#define AS3 __attribute__((address_space(3)))

// ---------------------------------------------------------------------------
// 0. transpose + f32->bf16: dst[c][r] = src[r][c], zero-pad c in [C, Cpad)
// ---------------------------------------------------------------------------
__global__ __launch_bounds__(256) void transpose_bf16_kernel(const float* __restrict__ src,
                                                             __hip_bfloat16* __restrict__ dst,
                                                             int R, int C, int Cpad) {
    __shared__ float t[32][33];
    const int c0 = blockIdx.x * 32, r0 = blockIdx.y * 32;
    const int tx = threadIdx.x & 31, ty = threadIdx.x >> 5;   // 32 x 8
    #pragma unroll
    for (int k = 0; k < 4; k++) {
        const int r = r0 + ty + 8 * k, c = c0 + tx;
        t[ty + 8 * k][tx] = (r < R && c < C) ? src[(size_t)r * C + c] : 0.f;
    }
    __syncthreads();
    #pragma unroll
    for (int k = 0; k < 4; k++) {
        const int c = c0 + ty + 8 * k, r = r0 + tx;
        if (c < Cpad && r < R) dst[(size_t)c * R + r] = __float2bfloat16(t[tx][ty + 8 * k]);
    }
}

// ---------------------------------------------------------------------------
// 1. fused LayerNorm -> bf16
// ---------------------------------------------------------------------------
__global__ __launch_bounds__(256) void ln_bf16_kernel(const float* __restrict__ x,
                                                      const float* __restrict__ g,
                                                      const float* __restrict__ bta,
                                                      __hip_bfloat16* __restrict__ xn) {
    const int row = blockIdx.x;
    const int tid = threadIdx.x;
    const float4 v = ((const float4*)(x + (size_t)row * DM))[tid];
    float s  = v.x + v.y + v.z + v.w;
    float sq = v.x*v.x + v.y*v.y + v.z*v.z + v.w*v.w;
    #pragma unroll
    for (int m = 1; m < 64; m <<= 1) {
        s  += __shfl_xor(s, m);
        sq += __shfl_xor(sq, m);
    }
    __shared__ float ss[4], ssq[4];
    const int w = tid >> 6;
    if ((tid & 63) == 0) { ss[w] = s; ssq[w] = sq; }
    __syncthreads();
    s  = ss[0] + ss[1] + ss[2] + ss[3];
    sq = ssq[0] + ssq[1] + ssq[2] + ssq[3];
    const float mu  = s * (1.f / DM);
    const float var = sq * (1.f / DM) - mu * mu;
    const float rs  = rsqrtf(var + 1e-5f);
    const float4 gv = ((const float4*)g)[tid];
    const float4 bv = ((const float4*)bta)[tid];
    __hip_bfloat16* op = xn + (size_t)row * DM + tid * 4;
    op[0] = __float2bfloat16((v.x - mu) * rs * gv.x + bv.x);
    op[1] = __float2bfloat16((v.y - mu) * rs * gv.y + bv.y);
    op[2] = __float2bfloat16((v.z - mu) * rs * gv.z + bv.z);
    op[3] = __float2bfloat16((v.w - mu) * rs * gv.w + bv.w);
}

// ---------------------------------------------------------------------------
// 2. bf16 MFMA GEMM (m97 structure): 128x128 tile, BK=32, 4 waves, 4x4 MFMA.
//    MODE 0: split epilogue -> O f32 (cols<DI), Oz bf16 (cols>=DI), stride DI
//    MODE 1: O f32 stride 128 (dbc) + Oz bf16 stride 64 for cols<64 (dt_r)
//    MODE 2: O f32 = acc + Add(row-major f32), stride DM (final GEMM+residual)
//    MODE 3: O f32 = softplus(acc + Add[col]) (bias), stride DI (dt)
// ---------------------------------------------------------------------------
template<int MODE>
__global__ __launch_bounds__(256) void mfma_gemm(const __hip_bfloat16* __restrict__ A,
                                                 const __hip_bfloat16* __restrict__ Bt,
                                                 float* __restrict__ O,
                                                 __hip_bfloat16* __restrict__ Oz,
                                                 const float* __restrict__ Add,
                                                 int K) {
    __shared__ __hip_bfloat16 As[128 * 32];
    __shared__ __hip_bfloat16 Bs[128 * 32];
    const int tid  = threadIdx.x;
    const int lane = tid & 63;
    const int w    = tid >> 6;
    const int row0 = blockIdx.y * 128, col0 = blockIdx.x * 128;
    const int wr0 = (w >> 1) * 64, wc0 = (w & 1) * 64;

    f32x4 acc[4][4];
    #pragma unroll
    for (int i = 0; i < 4; i++)
        #pragma unroll
        for (int j = 0; j < 4; j++) acc[i][j] = f32x4{0.f, 0.f, 0.f, 0.f};

    const int sm = tid >> 2;
    const int sk = (tid & 3) * 8;
    const __hip_bfloat16* gA = A  + (size_t)(row0 + sm) * K + sk;
    const __hip_bfloat16* gB = Bt + (size_t)(col0 + sm) * K + sk;
    __hip_bfloat16* lA = &As[tid * 8];
    __hip_bfloat16* lB = &Bs[tid * 8];
    const size_t g64 = (size_t)64 * K;

    const int fm = lane & 15;
    const int fq = (lane >> 4) * 8;

    for (int k0 = 0; k0 < K; k0 += 32) {
        __builtin_amdgcn_global_load_lds((const AS1 unsigned int*)(gA + k0),
                                         (AS3 unsigned int*)lA, 16, 0, 0);
        __builtin_amdgcn_global_load_lds((const AS1 unsigned int*)(gA + g64 + k0),
                                         (AS3 unsigned int*)(lA + 64 * 32), 16, 0, 0);
        __builtin_amdgcn_global_load_lds((const AS1 unsigned int*)(gB + k0),
                                         (AS3 unsigned int*)lB, 16, 0, 0);
        __builtin_amdgcn_global_load_lds((const AS1 unsigned int*)(gB + g64 + k0),
                                         (AS3 unsigned int*)(lB + 64 * 32), 16, 0, 0);
        __syncthreads();
        bf16x8 af[4], bfr[4];
        #pragma unroll
        for (int i = 0; i < 4; i++)
            af[i] = *(const bf16x8*)&As[(wr0 + i * 16 + fm) * 32 + fq];
        #pragma unroll
        for (int j = 0; j < 4; j++)
            bfr[j] = *(const bf16x8*)&Bs[(wc0 + j * 16 + fm) * 32 + fq];
        #pragma unroll
        for (int i = 0; i < 4; i++)
            #pragma unroll
            for (int j = 0; j < 4; j++)
                acc[i][j] = __builtin_amdgcn_mfma_f32_16x16x32_bf16(af[i], bfr[j], acc[i][j], 0, 0, 0);
        __syncthreads();
    }

    // epilogue: C/D layout col=lane&15, row=(lane>>4)*4+reg  [m89/m91 verified]
    #pragma unroll
    for (int i = 0; i < 4; i++) {
        #pragma unroll
        for (int j = 0; j < 4; j++) {
            #pragma unroll
            for (int r = 0; r < 4; r++) {
                const int row = row0 + wr0 + i * 16 + (lane >> 4) * 4 + r;
                const int col = col0 + wc0 + j * 16 + fm;
                const float v = acc[i][j][r];
                if (MODE == 0) {
                    if (col0 < DI) O[(size_t)row * DI + col] = v;
                    else           Oz[(size_t)row * DI + (col - DI)] = __float2bfloat16(v);
                } else if (MODE == 1) {
                    O[(size_t)row * 128 + col] = v;
                    if (col < DTR) Oz[(size_t)row * DTR + col] = __float2bfloat16(v);
                } else if (MODE == 2) {
                    O[(size_t)row * DM + col] = v + Add[(size_t)row * DM + col];
                } else {
                    const float t = v + Add[col];
                    O[(size_t)row * DI + col] = (t > 20.f) ? t : log1pf(__expf(t));
                }
            }
        }
    }
}

// ---------------------------------------------------------------------------
// 3. depthwise causal conv(4) + bias + SiLU.  u f32 [rows][DI] -> uc bf16
// ---------------------------------------------------------------------------
__global__ __launch_bounds__(256) void conv_silu_kernel(const float* __restrict__ u,
                                                        const float* __restrict__ cw,
                                                        const float* __restrict__ cb,
                                                        __hip_bfloat16* __restrict__ uc) {
    const int d  = blockIdx.x * 256 + threadIdx.x;
    const int b  = blockIdx.z;
    const int l0 = blockIdx.y * 16;
    const float w0 = cw[d * 4 + 0], w1 = cw[d * 4 + 1];
    const float w2 = cw[d * 4 + 2], w3 = cw[d * 4 + 3];
    const float bias = cb[d];
    const float* up = u + (size_t)(b * LL) * DI + d;
    float x0 = (l0 - 3 >= 0) ? up[(size_t)(l0 - 3) * DI] : 0.f;
    float x1 = (l0 - 2 >= 0) ? up[(size_t)(l0 - 2) * DI] : 0.f;
    float x2 = (l0 - 1 >= 0) ? up[(size_t)(l0 - 1) * DI] : 0.f;
    __hip_bfloat16* op = uc + (size_t)(b * LL + l0) * DI + d;
    #pragma unroll
    for (int i = 0; i < 16; i++) {
        const float x3 = up[(size_t)(l0 + i) * DI];
        const float v  = bias + w0 * x0 + w1 * x1 + w2 * x2 + w3 * x3;
        const float sig = __builtin_amdgcn_rcpf(1.f + __expf(-v));
        op[(size_t)i * DI] = __float2bfloat16(v * sig);
        x0 = x1; x1 = x2; x2 = x3;
    }
}

// ---------------------------------------------------------------------------
// 6a. scan pass 1 (thread-per-channel): h[16] in registers, B from LDS.
//     P = exp(a_s * sum dt) computed once at chunk end (exact).
// ---------------------------------------------------------------------------
__global__ __launch_bounds__(256) void scan_pass1_kernel(const float* __restrict__ dtb,
                                                         const __hip_bfloat16* __restrict__ uc,
                                                         const float* __restrict__ dbc,
                                                         const float* __restrict__ A_log,
                                                         float* __restrict__ hbuf,
                                                         float* __restrict__ Pbuf) {
    __shared__ float Bsh[CHUNK][16];      // 4 KB
    const int tid = threadIdx.x;
    const int d   = blockIdx.x * 256 + tid;
    const int c   = blockIdx.y;
    const int b   = blockIdx.z;
    const size_t row0 = (size_t)b * LL + (size_t)c * CHUNK;

    {
        const int r = tid >> 2, j4 = (tid & 3) * 4;
        *(float4*)&Bsh[r][j4] = *(const float4*)(dbc + (row0 + r) * 128 + DTR + j4);
    }
    float a[DST];
    #pragma unroll
    for (int q = 0; q < 4; q++) {
        const float4 t = *(const float4*)(A_log + (size_t)d * DST + q * 4);
        a[q * 4 + 0] = -__expf(t.x); a[q * 4 + 1] = -__expf(t.y);
        a[q * 4 + 2] = -__expf(t.z); a[q * 4 + 3] = -__expf(t.w);
    }
    __syncthreads();

    const float* dtp = dtb + row0 * DI + d;
    const __hip_bfloat16* ucp = uc + row0 * DI + d;

    float h[DST];
    #pragma unroll
    for (int s = 0; s < DST; s++) h[s] = 0.f;
    float sdt = 0.f;
    float dtv = dtp[0], ucv = __bfloat162float(ucp[0]);
    for (int l = 0; l < CHUNK; l++) {
        const int ln = (l + 1 < CHUNK) ? (l + 1) : l;
        const float dtn = dtp[(size_t)ln * DI];
        const float ucn = __bfloat162float(ucp[(size_t)ln * DI]);
        const float dtu = dtv * ucv;
        sdt += dtv;
        #pragma unroll
        for (int s = 0; s < DST; s++) {
            const float dA = __expf(dtv * a[s]);
            h[s] = fmaf(h[s], dA, dtu * Bsh[l][s]);
        }
        dtv = dtn; ucv = ucn;
    }
    float* hp = hbuf + (((size_t)b * NC + c) * DI + d) * DST;
    float* pp = Pbuf + (((size_t)b * NC + c) * DI + d) * DST;
    #pragma unroll
    for (int q = 0; q < 4; q++) {
        *(float4*)&hp[q * 4] = float4{h[q*4+0], h[q*4+1], h[q*4+2], h[q*4+3]};
        *(float4*)&pp[q * 4] = float4{__expf(sdt * a[q*4+0]), __expf(sdt * a[q*4+1]),
                                      __expf(sdt * a[q*4+2]), __expf(sdt * a[q*4+3])};
    }
}

// ---------------------------------------------------------------------------
// 6b. scan combine: rewrite hbuf[c] := h_in for chunk c
// ---------------------------------------------------------------------------
__global__ __launch_bounds__(256) void scan_combine_kernel(float* __restrict__ hbuf,
                                                           const float* __restrict__ Pbuf) {
    const size_t gid  = (size_t)blockIdx.x * 256 + threadIdx.x;
    const size_t b    = gid >> 15;             // DI*DST = 32768
    const size_t d16s = gid & 32767;
    float H = 0.f;
    #pragma unroll
    for (int c = 0; c < NC; c++) {
        const size_t idx = (b * NC + c) * (DI * DST) + d16s;
        const float hc = hbuf[idx];
        const float Pc = Pbuf[idx];
        hbuf[idx] = H;
        H = hc + Pc * H;
    }
}

// ---------------------------------------------------------------------------
// 6c. scan pass 3 (thread-per-channel): y = sum_s h_s*C_s in registers,
//     + D-skip + SiLU(z) gate; writes gated y bf16 in place over uc.
// ---------------------------------------------------------------------------
__global__ __launch_bounds__(256) void scan_pass3_kernel(const float* __restrict__ dtb,
                                                         __hip_bfloat16* uc,
                                                         const __hip_bfloat16* __restrict__ z,
                                                         const float* __restrict__ dbc,
                                                         const float* __restrict__ A_log,
                                                         const float* __restrict__ Dskip,
                                                         const float* __restrict__ hbuf) {
    __shared__ float BC[CHUNK][32];       // 8 KB: [0:16)=B, [16:32)=C
    const int tid = threadIdx.x;
    const int d   = blockIdx.x * 256 + tid;
    const int c   = blockIdx.y;
    const int b   = blockIdx.z;
    const size_t row0 = (size_t)b * LL + (size_t)c * CHUNK;

    #pragma unroll
    for (int i = 0; i < 2; i++) {
        const int idx = i * 256 + tid;
        const int r = idx >> 3, j4 = (idx & 7) * 4;
        *(float4*)&BC[r][j4] = *(const float4*)(dbc + (row0 + r) * 128 + DTR + j4);
    }
    float a[DST];
    #pragma unroll
    for (int q = 0; q < 4; q++) {
        const float4 t = *(const float4*)(A_log + (size_t)d * DST + q * 4);
        a[q * 4 + 0] = -__expf(t.x); a[q * 4 + 1] = -__expf(t.y);
        a[q * 4 + 2] = -__expf(t.z); a[q * 4 + 3] = -__expf(t.w);
    }
    const float dsk = Dskip[d];
    __syncthreads();

    const float* dtp = dtb + row0 * DI + d;
    __hip_bfloat16* ucp = uc + row0 * DI + d;
    const __hip_bfloat16* zp = z + row0 * DI + d;

    float h[DST];
    {
        const float* hp = hbuf + (((size_t)b * NC + c) * DI + d) * DST;
        #pragma unroll
        for (int q = 0; q < 4; q++) {
            const float4 t = *(const float4*)&hp[q * 4];
            h[q*4+0] = t.x; h[q*4+1] = t.y; h[q*4+2] = t.z; h[q*4+3] = t.w;
        }
    }
    float dtv = dtp[0];
    float ucv = __bfloat162float(ucp[0]);
    float zv  = __bfloat162float(zp[0]);
    for (int l = 0; l < CHUNK; l++) {
        const int ln = (l + 1 < CHUNK) ? (l + 1) : l;
        const float dtn = dtp[(size_t)ln * DI];
        const float ucn = __bfloat162float(ucp[(size_t)ln * DI]);
        const float zn  = __bfloat162float(zp[(size_t)ln * DI]);
        const float dtu = dtv * ucv;
        float y = 0.f;
        #pragma unroll
        for (int s = 0; s < DST; s++) {
            const float dA = __expf(dtv * a[s]);
            h[s] = fmaf(h[s], dA, dtu * BC[l][s]);
            y = fmaf(h[s], BC[l][16 + s], y);
        }
        const float yt  = fmaf(ucv, dsk, y);
        const float sig = __builtin_amdgcn_rcpf(1.f + __expf(-zv));
        ucp[(size_t)l * DI] = __float2bfloat16(yt * (zv * sig));
        dtv = dtn; ucv = ucn; zv = zn;
    }
}

// ---------------------------------------------------------------------------
extern "C" void kernel_launch(void* const* d_in, const int* in_sizes, int n_in,
                              void* d_out, int out_size, void* d_ws, size_t ws_size,
                              hipStream_t stream) {
    const float* x      = (const float*)d_in[0];
    const float* ln_g   = (const float*)d_in[1];
    const float* ln_b   = (const float*)d_in[2];
    const float* W_in   = (const float*)d_in[3];
    const float* conv_w = (const float*)d_in[4];
    const float* conv_b = (const float*)d_in[5];
    const float* W_x    = (const float*)d_in[6];
    const float* W_dt   = (const float*)d_in[7];
    const float* b_dt   = (const float*)d_in[8];
    const float* A_log  = (const float*)d_in[9];
    const float* Dskip  = (const float*)d_in[10];
    const float* W_out  = (const float*)d_in[11];
    float* out = (float*)d_out;

    // workspace layout (bytes), total 194.3 MB (proven budget: 195.1 MB)
    const size_t MB = 1024ull * 1024ull;
    char* wsb = (char*)d_ws;
    float*          u     = (float*)(wsb);                     // 64 MB: u -> dt
    __hip_bfloat16* z     = (__hip_bfloat16*)(wsb + 64 * MB);  // 32 MB
    __hip_bfloat16* uc    = (__hip_bfloat16*)(wsb + 96 * MB);  // 32 MB: uc -> yg
    __hip_bfloat16* xn    = (__hip_bfloat16*)(wsb + 128 * MB); // 16 MB
    __hip_bfloat16* WinT  = (__hip_bfloat16*)(wsb + 144 * MB); // 8 MB
    __hip_bfloat16* WoutT = (__hip_bfloat16*)(wsb + 152 * MB); // 4 MB
    __hip_bfloat16* WxT   = (__hip_bfloat16*)(wsb + 156 * MB); // 0.5 MB
    float*          dbc   = (float*)(wsb + 157 * MB);          // 4 MB [8192][128]
    float*          hbuf  = (float*)(wsb + 161 * MB);          // 16 MB
    float*          Pbuf  = (float*)(wsb + 177 * MB);          // 16 MB
    __hip_bfloat16* dbc64 = (__hip_bfloat16*)(wsb + 193 * MB); // 1 MB [8192][64]
    __hip_bfloat16* WdtT  = (__hip_bfloat16*)(wsb + 194 * MB); // 0.25 MB [2048][64]

    transpose_bf16_kernel<<<dim3(128, 32), 256, 0, stream>>>(W_in, WinT, DM, 2 * DI, 2 * DI);
    transpose_bf16_kernel<<<dim3(32, 64), 256, 0, stream>>>(W_out, WoutT, DI, DM, DM);
    transpose_bf16_kernel<<<dim3(4, 64), 256, 0, stream>>>(W_x, WxT, DI, 96, 128);
    transpose_bf16_kernel<<<dim3(64, 2), 256, 0, stream>>>(W_dt, WdtT, DTR, DI, DI);
    ln_bf16_kernel<<<ROWS, 256, 0, stream>>>(x, ln_g, ln_b, xn);
    mfma_gemm<0><<<dim3(32, 64), 256, 0, stream>>>(xn, WinT, u, z, nullptr, DM);
    conv_silu_kernel<<<dim3(DI / 256, LL / 16, BB), 256, 0, stream>>>(u, conv_w, conv_b, uc);
    mfma_gemm<1><<<dim3(1, 64), 256, 0, stream>>>(uc, WxT, dbc, dbc64, nullptr, DI);
    mfma_gemm<3><<<dim3(DI / 128, ROWS / 128), 256, 0, stream>>>(dbc64, WdtT, u, nullptr, b_dt, DTR);
    scan_pass1_kernel<<<dim3(DI / 256, NC, BB), 256, 0, stream>>>(u, uc, dbc, A_log, hbuf, Pbuf);
    scan_combine_kernel<<<(BB * DI * DST) / 256, 256, 0, stream>>>(hbuf, Pbuf);
    scan_pass3_kernel<<<dim3(DI / 256, NC, BB), 256, 0, stream>>>(u, uc, z, dbc, A_log, Dskip, hbuf);
    mfma_gemm<2><<<dim3(DM / 128, ROWS / 128), 256, 0, stream>>>(uc, WoutT, out, nullptr, x, DI);
}

// Round 7
// 490.360 us; speedup vs baseline: 1.2453x; 1.2453x over previous
//
#include <hip/hip_runtime.h>
#include <hip/hip_bf16.h>

// Problem constants
#define BB 4
#define LL 2048
#define DM 1024
#define DI 2048          // D_INNER
#define DST 16           // D_STATE
#define DTR 64           // DT_RANK
#define ROWS (BB*LL)     // 8192
#define NC 32            // scan chunks
#define CHUNK (LL/NC)    // 64

using bf16x8 = __attribute__((ext_vector_type(8))) __bf16;
using f32x4  = __attribute__((ext_vector_type(4))) float;

#define AS1 __attribute__((address_space(1)))
#define AS3 __attribute__((address_space(3)))

// ---------------------------------------------------------------------------
// 0. transpose + f32->bf16: dst[c][r] = src[r][c], zero-pad c in [C, Cpad)
// ---------------------------------------------------------------------------
__global__ __launch_bounds__(256) void transpose_bf16_kernel(const float* __restrict__ src,
                                                             __hip_bfloat16* __restrict__ dst,
                                                             int R, int C, int Cpad) {
    __shared__ float t[32][33];
    const int c0 = blockIdx.x * 32, r0 = blockIdx.y * 32;
    const int tx = threadIdx.x & 31, ty = threadIdx.x >> 5;   // 32 x 8
    #pragma unroll
    for (int k = 0; k < 4; k++) {
        const int r = r0 + ty + 8 * k, c = c0 + tx;
        t[ty + 8 * k][tx] = (r < R && c < C) ? src[(size_t)r * C + c] : 0.f;
    }
    __syncthreads();
    #pragma unroll
    for (int k = 0; k < 4; k++) {
        const int c = c0 + ty + 8 * k, r = r0 + tx;
        if (c < Cpad && r < R) dst[(size_t)c * R + r] = __float2bfloat16(t[tx][ty + 8 * k]);
    }
}

// ---------------------------------------------------------------------------
// 1. fused LayerNorm -> bf16
// ---------------------------------------------------------------------------
__global__ __launch_bounds__(256) void ln_bf16_kernel(const float* __restrict__ x,
                                                      const float* __restrict__ g,
                                                      const float* __restrict__ bta,
                                                      __hip_bfloat16* __restrict__ xn) {
    const int row = blockIdx.x;
    const int tid = threadIdx.x;
    const float4 v = ((const float4*)(x + (size_t)row * DM))[tid];
    float s  = v.x + v.y + v.z + v.w;
    float sq = v.x*v.x + v.y*v.y + v.z*v.z + v.w*v.w;
    #pragma unroll
    for (int m = 1; m < 64; m <<= 1) {
        s  += __shfl_xor(s, m);
        sq += __shfl_xor(sq, m);
    }
    __shared__ float ss[4], ssq[4];
    const int w = tid >> 6;
    if ((tid & 63) == 0) { ss[w] = s; ssq[w] = sq; }
    __syncthreads();
    s  = ss[0] + ss[1] + ss[2] + ss[3];
    sq = ssq[0] + ssq[1] + ssq[2] + ssq[3];
    const float mu  = s * (1.f / DM);
    const float var = sq * (1.f / DM) - mu * mu;
    const float rs  = rsqrtf(var + 1e-5f);
    const float4 gv = ((const float4*)g)[tid];
    const float4 bv = ((const float4*)bta)[tid];
    __hip_bfloat16* op = xn + (size_t)row * DM + tid * 4;
    op[0] = __float2bfloat16((v.x - mu) * rs * gv.x + bv.x);
    op[1] = __float2bfloat16((v.y - mu) * rs * gv.y + bv.y);
    op[2] = __float2bfloat16((v.z - mu) * rs * gv.z + bv.z);
    op[3] = __float2bfloat16((v.w - mu) * rs * gv.w + bv.w);
}

// ---------------------------------------------------------------------------
// 2. bf16 MFMA GEMM (m97 structure): 128x128 tile, BK=32, 4 waves, 4x4 MFMA.
//    MODE 0: Oz bf16 (cols<DI, ub), Ozb bf16 (cols>=DI, z), stride DI
//    MODE 1: O f32 stride 128 for 64<=col<96 (B,C) + Oz bf16 stride 64 col<64
//    MODE 2: O f32 = acc + Add(row-major f32), stride DM (final GEMM+residual)
//    MODE 3: Oz bf16 = softplus(acc + Add[col]) (bias), stride DI (dt)
// ---------------------------------------------------------------------------
template<int MODE>
__global__ __launch_bounds__(256) void mfma_gemm(const __hip_bfloat16* __restrict__ A,
                                                 const __hip_bfloat16* __restrict__ Bt,
                                                 float* __restrict__ O,
                                                 __hip_bfloat16* __restrict__ Oz,
                                                 __hip_bfloat16* __restrict__ Ozb,
                                                 const float* __restrict__ Add,
                                                 int K) {
    __shared__ __hip_bfloat16 As[128 * 32];
    __shared__ __hip_bfloat16 Bs[128 * 32];
    const int tid  = threadIdx.x;
    const int lane = tid & 63;
    const int w    = tid >> 6;
    const int row0 = blockIdx.y * 128, col0 = blockIdx.x * 128;
    const int wr0 = (w >> 1) * 64, wc0 = (w & 1) * 64;

    f32x4 acc[4][4];
    #pragma unroll
    for (int i = 0; i < 4; i++)
        #pragma unroll
        for (int j = 0; j < 4; j++) acc[i][j] = f32x4{0.f, 0.f, 0.f, 0.f};

    const int sm = tid >> 2;
    const int sk = (tid & 3) * 8;
    const __hip_bfloat16* gA = A  + (size_t)(row0 + sm) * K + sk;
    const __hip_bfloat16* gB = Bt + (size_t)(col0 + sm) * K + sk;
    __hip_bfloat16* lA = &As[tid * 8];
    __hip_bfloat16* lB = &Bs[tid * 8];
    const size_t g64 = (size_t)64 * K;

    const int fm = lane & 15;
    const int fq = (lane >> 4) * 8;

    for (int k0 = 0; k0 < K; k0 += 32) {
        __builtin_amdgcn_global_load_lds((const AS1 unsigned int*)(gA + k0),
                                         (AS3 unsigned int*)lA, 16, 0, 0);
        __builtin_amdgcn_global_load_lds((const AS1 unsigned int*)(gA + g64 + k0),
                                         (AS3 unsigned int*)(lA + 64 * 32), 16, 0, 0);
        __builtin_amdgcn_global_load_lds((const AS1 unsigned int*)(gB + k0),
                                         (AS3 unsigned int*)lB, 16, 0, 0);
        __builtin_amdgcn_global_load_lds((const AS1 unsigned int*)(gB + g64 + k0),
                                         (AS3 unsigned int*)(lB + 64 * 32), 16, 0, 0);
        __syncthreads();
        bf16x8 af[4], bfr[4];
        #pragma unroll
        for (int i = 0; i < 4; i++)
            af[i] = *(const bf16x8*)&As[(wr0 + i * 16 + fm) * 32 + fq];
        #pragma unroll
        for (int j = 0; j < 4; j++)
            bfr[j] = *(const bf16x8*)&Bs[(wc0 + j * 16 + fm) * 32 + fq];
        #pragma unroll
        for (int i = 0; i < 4; i++)
            #pragma unroll
            for (int j = 0; j < 4; j++)
                acc[i][j] = __builtin_amdgcn_mfma_f32_16x16x32_bf16(af[i], bfr[j], acc[i][j], 0, 0, 0);
        __syncthreads();
    }

    // epilogue: C/D layout col=lane&15, row=(lane>>4)*4+reg  [m89/m91 verified]
    #pragma unroll
    for (int i = 0; i < 4; i++) {
        #pragma unroll
        for (int j = 0; j < 4; j++) {
            #pragma unroll
            for (int r = 0; r < 4; r++) {
                const int row = row0 + wr0 + i * 16 + (lane >> 4) * 4 + r;
                const int col = col0 + wc0 + j * 16 + fm;
                const float v = acc[i][j][r];
                if (MODE == 0) {
                    if (col0 < DI) Oz[(size_t)row * DI + col] = __float2bfloat16(v);
                    else           Ozb[(size_t)row * DI + (col - DI)] = __float2bfloat16(v);
                } else if (MODE == 1) {
                    if (col >= DTR && col < DTR + 2 * DST)
                        O[(size_t)row * 128 + col] = v;
                    else if (col < DTR)
                        Oz[(size_t)row * DTR + col] = __float2bfloat16(v);
                } else if (MODE == 2) {
                    O[(size_t)row * DM + col] = v + Add[(size_t)row * DM + col];
                } else {
                    const float t  = v + Add[col];
                    const float sp = (t > 20.f) ? t : __logf(1.f + __expf(t));
                    Oz[(size_t)row * DI + col] = __float2bfloat16(sp);
                }
            }
        }
    }
}

// ---------------------------------------------------------------------------
// 3. depthwise causal conv(4) + bias + SiLU.  ub bf16 [rows][DI] -> uc bf16
// ---------------------------------------------------------------------------
__global__ __launch_bounds__(256) void conv_silu_kernel(const __hip_bfloat16* __restrict__ u,
                                                        const float* __restrict__ cw,
                                                        const float* __restrict__ cb,
                                                        __hip_bfloat16* __restrict__ uc) {
    const int d  = blockIdx.x * 256 + threadIdx.x;
    const int b  = blockIdx.z;
    const int l0 = blockIdx.y * 16;
    const float w0 = cw[d * 4 + 0], w1 = cw[d * 4 + 1];
    const float w2 = cw[d * 4 + 2], w3 = cw[d * 4 + 3];
    const float bias = cb[d];
    const __hip_bfloat16* up = u + (size_t)(b * LL) * DI + d;
    float x0 = (l0 - 3 >= 0) ? __bfloat162float(up[(size_t)(l0 - 3) * DI]) : 0.f;
    float x1 = (l0 - 2 >= 0) ? __bfloat162float(up[(size_t)(l0 - 2) * DI]) : 0.f;
    float x2 = (l0 - 1 >= 0) ? __bfloat162float(up[(size_t)(l0 - 1) * DI]) : 0.f;
    __hip_bfloat16* op = uc + (size_t)(b * LL + l0) * DI + d;
    #pragma unroll
    for (int i = 0; i < 16; i++) {
        const float x3 = __bfloat162float(up[(size_t)(l0 + i) * DI]);
        const float v  = bias + w0 * x0 + w1 * x1 + w2 * x2 + w3 * x3;
        const float sig = __builtin_amdgcn_rcpf(1.f + __expf(-v));
        op[(size_t)i * DI] = __float2bfloat16(v * sig);
        x0 = x1; x1 = x2; x2 = x3;
    }
}

// ---------------------------------------------------------------------------
// 6a. scan pass 1 (thread-per-channel): h[16] in registers, B from LDS.
//     P = exp(a_s * sum dt) computed once at chunk end (exact).
// ---------------------------------------------------------------------------
__global__ __launch_bounds__(256) void scan_pass1_kernel(const __hip_bfloat16* __restrict__ dtb,
                                                         const __hip_bfloat16* __restrict__ uc,
                                                         const float* __restrict__ dbc,
                                                         const float* __restrict__ A_log,
                                                         float* __restrict__ hbuf,
                                                         float* __restrict__ Pbuf) {
    __shared__ float Bsh[CHUNK][16];      // 4 KB
    const int tid = threadIdx.x;
    const int d   = blockIdx.x * 256 + tid;
    const int c   = blockIdx.y;
    const int b   = blockIdx.z;
    const size_t row0 = (size_t)b * LL + (size_t)c * CHUNK;

    {
        const int r = tid >> 2, j4 = (tid & 3) * 4;
        *(float4*)&Bsh[r][j4] = *(const float4*)(dbc + (row0 + r) * 128 + DTR + j4);
    }
    float a[DST];
    #pragma unroll
    for (int q = 0; q < 4; q++) {
        const float4 t = *(const float4*)(A_log + (size_t)d * DST + q * 4);
        a[q * 4 + 0] = -__expf(t.x); a[q * 4 + 1] = -__expf(t.y);
        a[q * 4 + 2] = -__expf(t.z); a[q * 4 + 3] = -__expf(t.w);
    }
    __syncthreads();

    const __hip_bfloat16* dtp = dtb + row0 * DI + d;
    const __hip_bfloat16* ucp = uc + row0 * DI + d;

    float h[DST];
    #pragma unroll
    for (int s = 0; s < DST; s++) h[s] = 0.f;
    float sdt = 0.f;
    float dtv = __bfloat162float(dtp[0]), ucv = __bfloat162float(ucp[0]);
    for (int l = 0; l < CHUNK; l++) {
        const int ln = (l + 1 < CHUNK) ? (l + 1) : l;
        const float dtn = __bfloat162float(dtp[(size_t)ln * DI]);
        const float ucn = __bfloat162float(ucp[(size_t)ln * DI]);
        const float dtu = dtv * ucv;
        sdt += dtv;
        #pragma unroll
        for (int s = 0; s < DST; s++) {
            const float dA = __expf(dtv * a[s]);
            h[s] = fmaf(h[s], dA, dtu * Bsh[l][s]);
        }
        dtv = dtn; ucv = ucn;
    }
    float* hp = hbuf + (((size_t)b * NC + c) * DI + d) * DST;
    float* pp = Pbuf + (((size_t)b * NC + c) * DI + d) * DST;
    #pragma unroll
    for (int q = 0; q < 4; q++) {
        *(float4*)&hp[q * 4] = float4{h[q*4+0], h[q*4+1], h[q*4+2], h[q*4+3]};
        *(float4*)&pp[q * 4] = float4{__expf(sdt * a[q*4+0]), __expf(sdt * a[q*4+1]),
                                      __expf(sdt * a[q*4+2]), __expf(sdt * a[q*4+3])};
    }
}

// ---------------------------------------------------------------------------
// 6b. scan combine: rewrite hbuf[c] := h_in for chunk c
// ---------------------------------------------------------------------------
__global__ __launch_bounds__(256) void scan_combine_kernel(float* __restrict__ hbuf,
                                                           const float* __restrict__ Pbuf) {
    const size_t gid  = (size_t)blockIdx.x * 256 + threadIdx.x;
    const size_t b    = gid >> 15;             // DI*DST = 32768
    const size_t d16s = gid & 32767;
    float H = 0.f;
    #pragma unroll
    for (int c = 0; c < NC; c++) {
        const size_t idx = (b * NC + c) * (DI * DST) + d16s;
        const float hc = hbuf[idx];
        const float Pc = Pbuf[idx];
        hbuf[idx] = H;
        H = hc + Pc * H;
    }
}

// ---------------------------------------------------------------------------
// 6c. scan pass 3 (thread-per-channel): y = sum_s h_s*C_s in registers,
//     + D-skip + SiLU(z) gate; writes gated y bf16 in place over uc.
// ---------------------------------------------------------------------------
__global__ __launch_bounds__(256) void scan_pass3_kernel(const __hip_bfloat16* __restrict__ dtb,
                                                         __hip_bfloat16* uc,
                                                         const __hip_bfloat16* __restrict__ z,
                                                         const float* __restrict__ dbc,
                                                         const float* __restrict__ A_log,
                                                         const float* __restrict__ Dskip,
                                                         const float* __restrict__ hbuf) {
    __shared__ float BC[CHUNK][32];       // 8 KB: [0:16)=B, [16:32)=C
    const int tid = threadIdx.x;
    const int d   = blockIdx.x * 256 + tid;
    const int c   = blockIdx.y;
    const int b   = blockIdx.z;
    const size_t row0 = (size_t)b * LL + (size_t)c * CHUNK;

    #pragma unroll
    for (int i = 0; i < 2; i++) {
        const int idx = i * 256 + tid;
        const int r = idx >> 3, j4 = (idx & 7) * 4;
        *(float4*)&BC[r][j4] = *(const float4*)(dbc + (row0 + r) * 128 + DTR + j4);
    }
    float a[DST];
    #pragma unroll
    for (int q = 0; q < 4; q++) {
        const float4 t = *(const float4*)(A_log + (size_t)d * DST + q * 4);
        a[q * 4 + 0] = -__expf(t.x); a[q * 4 + 1] = -__expf(t.y);
        a[q * 4 + 2] = -__expf(t.z); a[q * 4 + 3] = -__expf(t.w);
    }
    const float dsk = Dskip[d];
    __syncthreads();

    const __hip_bfloat16* dtp = dtb + row0 * DI + d;
    __hip_bfloat16* ucp = uc + row0 * DI + d;
    const __hip_bfloat16* zp = z + row0 * DI + d;

    float h[DST];
    {
        const float* hp = hbuf + (((size_t)b * NC + c) * DI + d) * DST;
        #pragma unroll
        for (int q = 0; q < 4; q++) {
            const float4 t = *(const float4*)&hp[q * 4];
            h[q*4+0] = t.x; h[q*4+1] = t.y; h[q*4+2] = t.z; h[q*4+3] = t.w;
        }
    }
    float dtv = __bfloat162float(dtp[0]);
    float ucv = __bfloat162float(ucp[0]);
    float zv  = __bfloat162float(zp[0]);
    for (int l = 0; l < CHUNK; l++) {
        const int ln = (l + 1 < CHUNK) ? (l + 1) : l;
        const float dtn = __bfloat162float(dtp[(size_t)ln * DI]);
        const float ucn = __bfloat162float(ucp[(size_t)ln * DI]);
        const float zn  = __bfloat162float(zp[(size_t)ln * DI]);
        const float dtu = dtv * ucv;
        float y = 0.f;
        #pragma unroll
        for (int s = 0; s < DST; s++) {
            const float dA = __expf(dtv * a[s]);
            h[s] = fmaf(h[s], dA, dtu * BC[l][s]);
            y = fmaf(h[s], BC[l][16 + s], y);
        }
        const float yt  = fmaf(ucv, dsk, y);
        const float sig = __builtin_amdgcn_rcpf(1.f + __expf(-zv));
        ucp[(size_t)l * DI] = __float2bfloat16(yt * (zv * sig));
        dtv = dtn; ucv = ucn; zv = zn;
    }
}

// ---------------------------------------------------------------------------
extern "C" void kernel_launch(void* const* d_in, const int* in_sizes, int n_in,
                              void* d_out, int out_size, void* d_ws, size_t ws_size,
                              hipStream_t stream) {
    const float* x      = (const float*)d_in[0];
    const float* ln_g   = (const float*)d_in[1];
    const float* ln_b   = (const float*)d_in[2];
    const float* W_in   = (const float*)d_in[3];
    const float* conv_w = (const float*)d_in[4];
    const float* conv_b = (const float*)d_in[5];
    const float* W_x    = (const float*)d_in[6];
    const float* W_dt   = (const float*)d_in[7];
    const float* b_dt   = (const float*)d_in[8];
    const float* A_log  = (const float*)d_in[9];
    const float* Dskip  = (const float*)d_in[10];
    const float* W_out  = (const float*)d_in[11];
    float* out = (float*)d_out;

    // workspace layout (bytes), total ~162.3 MB (proven budget: 195 MB)
    const size_t MB = 1024ull * 1024ull;
    char* wsb = (char*)d_ws;
    __hip_bfloat16* ub    = (__hip_bfloat16*)(wsb);            // 32 MB: u -> dt
    __hip_bfloat16* z     = (__hip_bfloat16*)(wsb + 32 * MB);  // 32 MB
    __hip_bfloat16* uc    = (__hip_bfloat16*)(wsb + 64 * MB);  // 32 MB: uc -> yg
    __hip_bfloat16* xn    = (__hip_bfloat16*)(wsb + 96 * MB);  // 16 MB
    __hip_bfloat16* WinT  = (__hip_bfloat16*)(wsb + 112 * MB); // 8 MB
    __hip_bfloat16* WoutT = (__hip_bfloat16*)(wsb + 120 * MB); // 4 MB
    __hip_bfloat16* WxT   = (__hip_bfloat16*)(wsb + 124 * MB); // 0.5 MB
    float*          dbc   = (float*)(wsb + 125 * MB);          // 4 MB [8192][128]
    float*          hbuf  = (float*)(wsb + 129 * MB);          // 16 MB
    float*          Pbuf  = (float*)(wsb + 145 * MB);          // 16 MB
    __hip_bfloat16* dbc64 = (__hip_bfloat16*)(wsb + 161 * MB); // 1 MB [8192][64]
    __hip_bfloat16* WdtT  = (__hip_bfloat16*)(wsb + 162 * MB); // 0.25 MB [2048][64]
    __hip_bfloat16* dtb   = ub;                                // reuse (u dead after conv)

    transpose_bf16_kernel<<<dim3(128, 32), 256, 0, stream>>>(W_in, WinT, DM, 2 * DI, 2 * DI);
    transpose_bf16_kernel<<<dim3(32, 64), 256, 0, stream>>>(W_out, WoutT, DI, DM, DM);
    transpose_bf16_kernel<<<dim3(4, 64), 256, 0, stream>>>(W_x, WxT, DI, 96, 128);
    transpose_bf16_kernel<<<dim3(64, 2), 256, 0, stream>>>(W_dt, WdtT, DTR, DI, DI);
    ln_bf16_kernel<<<ROWS, 256, 0, stream>>>(x, ln_g, ln_b, xn);
    mfma_gemm<0><<<dim3(32, 64), 256, 0, stream>>>(xn, WinT, nullptr, ub, z, nullptr, DM);
    conv_silu_kernel<<<dim3(DI / 256, LL / 16, BB), 256, 0, stream>>>(ub, conv_w, conv_b, uc);
    mfma_gemm<1><<<dim3(1, 64), 256, 0, stream>>>(uc, WxT, dbc, dbc64, nullptr, nullptr, DI);
    mfma_gemm<3><<<dim3(DI / 128, ROWS / 128), 256, 0, stream>>>(dbc64, WdtT, nullptr, dtb, nullptr, b_dt, DTR);
    scan_pass1_kernel<<<dim3(DI / 256, NC, BB), 256, 0, stream>>>(dtb, uc, dbc, A_log, hbuf, Pbuf);
    scan_combine_kernel<<<(BB * DI * DST) / 256, 256, 0, stream>>>(hbuf, Pbuf);
    scan_pass3_kernel<<<dim3(DI / 256, NC, BB), 256, 0, stream>>>(dtb, uc, z, dbc, A_log, Dskip, hbuf);
    mfma_gemm<2><<<dim3(DM / 128, ROWS / 128), 256, 0, stream>>>(uc, WoutT, out, nullptr, nullptr, x, DI);
}

// Round 8
// 459.898 us; speedup vs baseline: 1.3278x; 1.0662x over previous
//
#include <hip/hip_runtime.h>
#include <hip/hip_bf16.h>

// Problem constants
#define BB 4
#define LL 2048
#define DM 1024
#define DI 2048          // D_INNER
#define DST 16           // D_STATE
#define DTR 64           // DT_RANK
#define ROWS (BB*LL)     // 8192
#define NC 32            // scan chunks
#define CHUNK (LL/NC)    // 64

using bf16x8 = __attribute__((ext_vector_type(8))) __bf16;
using f32x4  = __attribute__((ext_vector_type(4))) float;

#define AS1 __attribute__((address_space(1)))
#define AS3 __attribute__((address_space(3)))

// ---------------------------------------------------------------------------
// 0. transpose + f32->bf16: dst[c][r] = src[r][c], zero-pad c in [C, Cpad)
// ---------------------------------------------------------------------------
__global__ __launch_bounds__(256) void transpose_bf16_kernel(const float* __restrict__ src,
                                                             __hip_bfloat16* __restrict__ dst,
                                                             int R, int C, int Cpad) {
    __shared__ float t[32][33];
    const int c0 = blockIdx.x * 32, r0 = blockIdx.y * 32;
    const int tx = threadIdx.x & 31, ty = threadIdx.x >> 5;   // 32 x 8
    #pragma unroll
    for (int k = 0; k < 4; k++) {
        const int r = r0 + ty + 8 * k, c = c0 + tx;
        t[ty + 8 * k][tx] = (r < R && c < C) ? src[(size_t)r * C + c] : 0.f;
    }
    __syncthreads();
    #pragma unroll
    for (int k = 0; k < 4; k++) {
        const int c = c0 + ty + 8 * k, r = r0 + tx;
        if (c < Cpad && r < R) dst[(size_t)c * R + r] = __float2bfloat16(t[tx][ty + 8 * k]);
    }
}

// ---------------------------------------------------------------------------
// 1. fused LayerNorm -> bf16
// ---------------------------------------------------------------------------
__global__ __launch_bounds__(256) void ln_bf16_kernel(const float* __restrict__ x,
                                                      const float* __restrict__ g,
                                                      const float* __restrict__ bta,
                                                      __hip_bfloat16* __restrict__ xn) {
    const int row = blockIdx.x;
    const int tid = threadIdx.x;
    const float4 v = ((const float4*)(x + (size_t)row * DM))[tid];
    float s  = v.x + v.y + v.z + v.w;
    float sq = v.x*v.x + v.y*v.y + v.z*v.z + v.w*v.w;
    #pragma unroll
    for (int m = 1; m < 64; m <<= 1) {
        s  += __shfl_xor(s, m);
        sq += __shfl_xor(sq, m);
    }
    __shared__ float ss[4], ssq[4];
    const int w = tid >> 6;
    if ((tid & 63) == 0) { ss[w] = s; ssq[w] = sq; }
    __syncthreads();
    s  = ss[0] + ss[1] + ss[2] + ss[3];
    sq = ssq[0] + ssq[1] + ssq[2] + ssq[3];
    const float mu  = s * (1.f / DM);
    const float var = sq * (1.f / DM) - mu * mu;
    const float rs  = rsqrtf(var + 1e-5f);
    const float4 gv = ((const float4*)g)[tid];
    const float4 bv = ((const float4*)bta)[tid];
    __hip_bfloat16* op = xn + (size_t)row * DM + tid * 4;
    op[0] = __float2bfloat16((v.x - mu) * rs * gv.x + bv.x);
    op[1] = __float2bfloat16((v.y - mu) * rs * gv.y + bv.y);
    op[2] = __float2bfloat16((v.z - mu) * rs * gv.z + bv.z);
    op[3] = __float2bfloat16((v.w - mu) * rs * gv.w + bv.w);
}

// ---------------------------------------------------------------------------
// 2. bf16 MFMA GEMM: 128x128 tile, BK=64 staged as TWO BK=32 planes
//    (keeps 64B LDS row stride -> low bank conflicts), 4 waves, 4x4 MFMA,
//    grouped block swizzle (GM=8) for L2/HBM locality.
//    MODE 0: Oz bf16 (cols<DI, ub), Ozb bf16 (cols>=DI, z), stride DI
//    MODE 1: O f32 stride 128 for 64<=col<96 (B,C) + Oz bf16 stride 64 col<64
//    MODE 2: O f32 = acc + Add(row-major f32), stride DM (final GEMM+residual)
//    MODE 3: Oz bf16 = softplus(acc + Add[col]) (bias), stride DI (dt)
// ---------------------------------------------------------------------------
template<int MODE>
__global__ __launch_bounds__(256) void mfma_gemm(const __hip_bfloat16* __restrict__ A,
                                                 const __hip_bfloat16* __restrict__ Bt,
                                                 float* __restrict__ O,
                                                 __hip_bfloat16* __restrict__ Oz,
                                                 __hip_bfloat16* __restrict__ Ozb,
                                                 const float* __restrict__ Add,
                                                 int K) {
    __shared__ __hip_bfloat16 As[2 * 128 * 32];   // 16 KB
    __shared__ __hip_bfloat16 Bs[2 * 128 * 32];   // 16 KB
    const int tid  = threadIdx.x;
    const int lane = tid & 63;
    const int w    = tid >> 6;

    // grouped swizzle: supergroup of GM row-tiles, walk cols within group
    const int nbx = gridDim.x, nby = gridDim.y;
    const int lid  = blockIdx.y * nbx + blockIdx.x;
    const int span = 8 * nbx;
    const int grp  = lid / span;
    const int fm0  = grp * 8;
    const int gsz  = min(nby - fm0, 8);
    const int by   = fm0 + (lid % gsz);
    const int bx   = (lid % span) / gsz;

    const int row0 = by * 128, col0 = bx * 128;
    const int wr0 = (w >> 1) * 64, wc0 = (w & 1) * 64;

    f32x4 acc[4][4];
    #pragma unroll
    for (int i = 0; i < 4; i++)
        #pragma unroll
        for (int j = 0; j < 4; j++) acc[i][j] = f32x4{0.f, 0.f, 0.f, 0.f};

    const int fm = lane & 15;
    const int fq = (lane >> 4) * 8;

    for (int k0 = 0; k0 < K; k0 += 64) {
        // stage 2 planes x 128 rows x 32 k; chunk c = 16B; dst = base+lane*16
        #pragma unroll
        for (int j = 0; j < 4; j++) {
            const int c   = w * 256 + j * 64 + lane;
            const int p   = c >> 9;
            const int row = (c >> 2) & 127;
            const int kq  = (c & 3) * 8;
            const int gk  = k0 + p * 32 + kq;
            __builtin_amdgcn_global_load_lds(
                (const AS1 unsigned int*)(A + (size_t)(row0 + row) * K + gk),
                (AS3 unsigned int*)(As + c * 8), 16, 0, 0);
            __builtin_amdgcn_global_load_lds(
                (const AS1 unsigned int*)(Bt + (size_t)(col0 + row) * K + gk),
                (AS3 unsigned int*)(Bs + c * 8), 16, 0, 0);
        }
        __syncthreads();
        #pragma unroll
        for (int half = 0; half < 2; half++) {
            bf16x8 af[4], bfr[4];
            #pragma unroll
            for (int i = 0; i < 4; i++)
                af[i] = *(const bf16x8*)&As[half * 4096 + (wr0 + i * 16 + fm) * 32 + fq];
            #pragma unroll
            for (int j = 0; j < 4; j++)
                bfr[j] = *(const bf16x8*)&Bs[half * 4096 + (wc0 + j * 16 + fm) * 32 + fq];
            #pragma unroll
            for (int i = 0; i < 4; i++)
                #pragma unroll
                for (int j = 0; j < 4; j++)
                    acc[i][j] = __builtin_amdgcn_mfma_f32_16x16x32_bf16(af[i], bfr[j], acc[i][j], 0, 0, 0);
        }
        __syncthreads();
    }

    // epilogue: C/D layout col=lane&15, row=(lane>>4)*4+reg  [m89/m91 verified]
    #pragma unroll
    for (int i = 0; i < 4; i++) {
        #pragma unroll
        for (int j = 0; j < 4; j++) {
            #pragma unroll
            for (int r = 0; r < 4; r++) {
                const int row = row0 + wr0 + i * 16 + (lane >> 4) * 4 + r;
                const int col = col0 + wc0 + j * 16 + fm;
                const float v = acc[i][j][r];
                if (MODE == 0) {
                    if (col0 < DI) Oz[(size_t)row * DI + col] = __float2bfloat16(v);
                    else           Ozb[(size_t)row * DI + (col - DI)] = __float2bfloat16(v);
                } else if (MODE == 1) {
                    if (col >= DTR && col < DTR + 2 * DST)
                        O[(size_t)row * 128 + col] = v;
                    else if (col < DTR)
                        Oz[(size_t)row * DTR + col] = __float2bfloat16(v);
                } else if (MODE == 2) {
                    O[(size_t)row * DM + col] = v + Add[(size_t)row * DM + col];
                } else {
                    const float t  = v + Add[col];
                    const float sp = (t > 20.f) ? t : __logf(1.f + __expf(t));
                    Oz[(size_t)row * DI + col] = __float2bfloat16(sp);
                }
            }
        }
    }
}

// ---------------------------------------------------------------------------
// 3. depthwise causal conv(4) + bias + SiLU.  ub bf16 [rows][DI] -> uc bf16
// ---------------------------------------------------------------------------
__global__ __launch_bounds__(256) void conv_silu_kernel(const __hip_bfloat16* __restrict__ u,
                                                        const float* __restrict__ cw,
                                                        const float* __restrict__ cb,
                                                        __hip_bfloat16* __restrict__ uc) {
    const int d  = blockIdx.x * 256 + threadIdx.x;
    const int b  = blockIdx.z;
    const int l0 = blockIdx.y * 16;
    const float w0 = cw[d * 4 + 0], w1 = cw[d * 4 + 1];
    const float w2 = cw[d * 4 + 2], w3 = cw[d * 4 + 3];
    const float bias = cb[d];
    const __hip_bfloat16* up = u + (size_t)(b * LL) * DI + d;
    float x0 = (l0 - 3 >= 0) ? __bfloat162float(up[(size_t)(l0 - 3) * DI]) : 0.f;
    float x1 = (l0 - 2 >= 0) ? __bfloat162float(up[(size_t)(l0 - 2) * DI]) : 0.f;
    float x2 = (l0 - 1 >= 0) ? __bfloat162float(up[(size_t)(l0 - 1) * DI]) : 0.f;
    __hip_bfloat16* op = uc + (size_t)(b * LL + l0) * DI + d;
    #pragma unroll
    for (int i = 0; i < 16; i++) {
        const float x3 = __bfloat162float(up[(size_t)(l0 + i) * DI]);
        const float v  = bias + w0 * x0 + w1 * x1 + w2 * x2 + w3 * x3;
        const float sig = __builtin_amdgcn_rcpf(1.f + __expf(-v));
        op[(size_t)i * DI] = __float2bfloat16(v * sig);
        x0 = x1; x1 = x2; x2 = x3;
    }
}

// ---------------------------------------------------------------------------
// 6a. scan pass 1 (thread-per-channel): h[16] in registers, B from LDS.
// ---------------------------------------------------------------------------
__global__ __launch_bounds__(256) void scan_pass1_kernel(const __hip_bfloat16* __restrict__ dtb,
                                                         const __hip_bfloat16* __restrict__ uc,
                                                         const float* __restrict__ dbc,
                                                         const float* __restrict__ A_log,
                                                         float* __restrict__ hbuf,
                                                         float* __restrict__ Pbuf) {
    __shared__ float Bsh[CHUNK][16];      // 4 KB
    const int tid = threadIdx.x;
    const int d   = blockIdx.x * 256 + tid;
    const int c   = blockIdx.y;
    const int b   = blockIdx.z;
    const size_t row0 = (size_t)b * LL + (size_t)c * CHUNK;

    {
        const int r = tid >> 2, j4 = (tid & 3) * 4;
        *(float4*)&Bsh[r][j4] = *(const float4*)(dbc + (row0 + r) * 128 + DTR + j4);
    }
    float a[DST];
    #pragma unroll
    for (int q = 0; q < 4; q++) {
        const float4 t = *(const float4*)(A_log + (size_t)d * DST + q * 4);
        a[q * 4 + 0] = -__expf(t.x); a[q * 4 + 1] = -__expf(t.y);
        a[q * 4 + 2] = -__expf(t.z); a[q * 4 + 3] = -__expf(t.w);
    }
    __syncthreads();

    const __hip_bfloat16* dtp = dtb + row0 * DI + d;
    const __hip_bfloat16* ucp = uc + row0 * DI + d;

    float h[DST];
    #pragma unroll
    for (int s = 0; s < DST; s++) h[s] = 0.f;
    float sdt = 0.f;
    float dtv = __bfloat162float(dtp[0]), ucv = __bfloat162float(ucp[0]);
    for (int l = 0; l < CHUNK; l++) {
        const int ln = (l + 1 < CHUNK) ? (l + 1) : l;
        const float dtn = __bfloat162float(dtp[(size_t)ln * DI]);
        const float ucn = __bfloat162float(ucp[(size_t)ln * DI]);
        const float dtu = dtv * ucv;
        sdt += dtv;
        #pragma unroll
        for (int s = 0; s < DST; s++) {
            const float dA = __expf(dtv * a[s]);
            h[s] = fmaf(h[s], dA, dtu * Bsh[l][s]);
        }
        dtv = dtn; ucv = ucn;
    }
    float* hp = hbuf + (((size_t)b * NC + c) * DI + d) * DST;
    float* pp = Pbuf + (((size_t)b * NC + c) * DI + d) * DST;
    #pragma unroll
    for (int q = 0; q < 4; q++) {
        *(float4*)&hp[q * 4] = float4{h[q*4+0], h[q*4+1], h[q*4+2], h[q*4+3]};
        *(float4*)&pp[q * 4] = float4{__expf(sdt * a[q*4+0]), __expf(sdt * a[q*4+1]),
                                      __expf(sdt * a[q*4+2]), __expf(sdt * a[q*4+3])};
    }
}

// ---------------------------------------------------------------------------
// 6b. scan combine: rewrite hbuf[c] := h_in for chunk c
// ---------------------------------------------------------------------------
__global__ __launch_bounds__(256) void scan_combine_kernel(float* __restrict__ hbuf,
                                                           const float* __restrict__ Pbuf) {
    const size_t gid  = (size_t)blockIdx.x * 256 + threadIdx.x;
    const size_t b    = gid >> 15;             // DI*DST = 32768
    const size_t d16s = gid & 32767;
    float H = 0.f;
    #pragma unroll
    for (int c = 0; c < NC; c++) {
        const size_t idx = (b * NC + c) * (DI * DST) + d16s;
        const float hc = hbuf[idx];
        const float Pc = Pbuf[idx];
        hbuf[idx] = H;
        H = hc + Pc * H;
    }
}

// ---------------------------------------------------------------------------
// 6c. scan pass 3 (thread-per-channel): y + D-skip + SiLU(z) gate, in place.
// ---------------------------------------------------------------------------
__global__ __launch_bounds__(256) void scan_pass3_kernel(const __hip_bfloat16* __restrict__ dtb,
                                                         __hip_bfloat16* uc,
                                                         const __hip_bfloat16* __restrict__ z,
                                                         const float* __restrict__ dbc,
                                                         const float* __restrict__ A_log,
                                                         const float* __restrict__ Dskip,
                                                         const float* __restrict__ hbuf) {
    __shared__ float BC[CHUNK][32];       // 8 KB: [0:16)=B, [16:32)=C
    const int tid = threadIdx.x;
    const int d   = blockIdx.x * 256 + tid;
    const int c   = blockIdx.y;
    const int b   = blockIdx.z;
    const size_t row0 = (size_t)b * LL + (size_t)c * CHUNK;

    #pragma unroll
    for (int i = 0; i < 2; i++) {
        const int idx = i * 256 + tid;
        const int r = idx >> 3, j4 = (idx & 7) * 4;
        *(float4*)&BC[r][j4] = *(const float4*)(dbc + (row0 + r) * 128 + DTR + j4);
    }
    float a[DST];
    #pragma unroll
    for (int q = 0; q < 4; q++) {
        const float4 t = *(const float4*)(A_log + (size_t)d * DST + q * 4);
        a[q * 4 + 0] = -__expf(t.x); a[q * 4 + 1] = -__expf(t.y);
        a[q * 4 + 2] = -__expf(t.z); a[q * 4 + 3] = -__expf(t.w);
    }
    const float dsk = Dskip[d];
    __syncthreads();

    const __hip_bfloat16* dtp = dtb + row0 * DI + d;
    __hip_bfloat16* ucp = uc + row0 * DI + d;
    const __hip_bfloat16* zp = z + row0 * DI + d;

    float h[DST];
    {
        const float* hp = hbuf + (((size_t)b * NC + c) * DI + d) * DST;
        #pragma unroll
        for (int q = 0; q < 4; q++) {
            const float4 t = *(const float4*)&hp[q * 4];
            h[q*4+0] = t.x; h[q*4+1] = t.y; h[q*4+2] = t.z; h[q*4+3] = t.w;
        }
    }
    float dtv = __bfloat162float(dtp[0]);
    float ucv = __bfloat162float(ucp[0]);
    float zv  = __bfloat162float(zp[0]);
    for (int l = 0; l < CHUNK; l++) {
        const int ln = (l + 1 < CHUNK) ? (l + 1) : l;
        const float dtn = __bfloat162float(dtp[(size_t)ln * DI]);
        const float ucn = __bfloat162float(ucp[(size_t)ln * DI]);
        const float zn  = __bfloat162float(zp[(size_t)ln * DI]);
        const float dtu = dtv * ucv;
        float y = 0.f;
        #pragma unroll
        for (int s = 0; s < DST; s++) {
            const float dA = __expf(dtv * a[s]);
            h[s] = fmaf(h[s], dA, dtu * BC[l][s]);
            y = fmaf(h[s], BC[l][16 + s], y);
        }
        const float yt  = fmaf(ucv, dsk, y);
        const float sig = __builtin_amdgcn_rcpf(1.f + __expf(-zv));
        ucp[(size_t)l * DI] = __float2bfloat16(yt * (zv * sig));
        dtv = dtn; ucv = ucn; zv = zn;
    }
}

// ---------------------------------------------------------------------------
extern "C" void kernel_launch(void* const* d_in, const int* in_sizes, int n_in,
                              void* d_out, int out_size, void* d_ws, size_t ws_size,
                              hipStream_t stream) {
    const float* x      = (const float*)d_in[0];
    const float* ln_g   = (const float*)d_in[1];
    const float* ln_b   = (const float*)d_in[2];
    const float* W_in   = (const float*)d_in[3];
    const float* conv_w = (const float*)d_in[4];
    const float* conv_b = (const float*)d_in[5];
    const float* W_x    = (const float*)d_in[6];
    const float* W_dt   = (const float*)d_in[7];
    const float* b_dt   = (const float*)d_in[8];
    const float* A_log  = (const float*)d_in[9];
    const float* Dskip  = (const float*)d_in[10];
    const float* W_out  = (const float*)d_in[11];
    float* out = (float*)d_out;

    // workspace layout (bytes), total ~162.3 MB (proven budget: 195 MB)
    const size_t MB = 1024ull * 1024ull;
    char* wsb = (char*)d_ws;
    __hip_bfloat16* ub    = (__hip_bfloat16*)(wsb);            // 32 MB: u -> dt
    __hip_bfloat16* z     = (__hip_bfloat16*)(wsb + 32 * MB);  // 32 MB
    __hip_bfloat16* uc    = (__hip_bfloat16*)(wsb + 64 * MB);  // 32 MB: uc -> yg
    __hip_bfloat16* xn    = (__hip_bfloat16*)(wsb + 96 * MB);  // 16 MB
    __hip_bfloat16* WinT  = (__hip_bfloat16*)(wsb + 112 * MB); // 8 MB
    __hip_bfloat16* WoutT = (__hip_bfloat16*)(wsb + 120 * MB); // 4 MB
    __hip_bfloat16* WxT   = (__hip_bfloat16*)(wsb + 124 * MB); // 0.5 MB
    float*          dbc   = (float*)(wsb + 125 * MB);          // 4 MB [8192][128]
    float*          hbuf  = (float*)(wsb + 129 * MB);          // 16 MB
    float*          Pbuf  = (float*)(wsb + 145 * MB);          // 16 MB
    __hip_bfloat16* dbc64 = (__hip_bfloat16*)(wsb + 161 * MB); // 1 MB [8192][64]
    __hip_bfloat16* WdtT  = (__hip_bfloat16*)(wsb + 162 * MB); // 0.25 MB [2048][64]
    __hip_bfloat16* dtb   = ub;                                // reuse (u dead after conv)

    transpose_bf16_kernel<<<dim3(128, 32), 256, 0, stream>>>(W_in, WinT, DM, 2 * DI, 2 * DI);
    transpose_bf16_kernel<<<dim3(32, 64), 256, 0, stream>>>(W_out, WoutT, DI, DM, DM);
    transpose_bf16_kernel<<<dim3(4, 64), 256, 0, stream>>>(W_x, WxT, DI, 96, 128);
    transpose_bf16_kernel<<<dim3(64, 2), 256, 0, stream>>>(W_dt, WdtT, DTR, DI, DI);
    ln_bf16_kernel<<<ROWS, 256, 0, stream>>>(x, ln_g, ln_b, xn);
    mfma_gemm<0><<<dim3(32, 64), 256, 0, stream>>>(xn, WinT, nullptr, ub, z, nullptr, DM);
    conv_silu_kernel<<<dim3(DI / 256, LL / 16, BB), 256, 0, stream>>>(ub, conv_w, conv_b, uc);
    mfma_gemm<1><<<dim3(1, 64), 256, 0, stream>>>(uc, WxT, dbc, dbc64, nullptr, nullptr, DI);
    mfma_gemm<3><<<dim3(DI / 128, ROWS / 128), 256, 0, stream>>>(dbc64, WdtT, nullptr, dtb, nullptr, b_dt, DTR);
    scan_pass1_kernel<<<dim3(DI / 256, NC, BB), 256, 0, stream>>>(dtb, uc, dbc, A_log, hbuf, Pbuf);
    scan_combine_kernel<<<(BB * DI * DST) / 256, 256, 0, stream>>>(hbuf, Pbuf);
    scan_pass3_kernel<<<dim3(DI / 256, NC, BB), 256, 0, stream>>>(dtb, uc, z, dbc, A_log, Dskip, hbuf);
    mfma_gemm<2><<<dim3(DM / 128, ROWS / 128), 256, 0, stream>>>(uc, WoutT, out, nullptr, nullptr, x, DI);
}

// Round 9
// 432.726 us; speedup vs baseline: 1.4111x; 1.0628x over previous
//
#include <hip/hip_runtime.h>
#include <hip/hip_bf16.h>

// Problem constants
#define BB 4
#define LL 2048
#define DM 1024
#define DI 2048          // D_INNER
#define DST 16           // D_STATE
#define DTR 64           // DT_RANK
#define ROWS (BB*LL)     // 8192
#define NC 32            // scan chunks
#define CHUNK (LL/NC)    // 64

using bf16x8 = __attribute__((ext_vector_type(8))) __bf16;
using f32x4  = __attribute__((ext_vector_type(4))) float;

#define AS1 __attribute__((address_space(1)))
#define AS3 __attribute__((address_space(3)))

// ---------------------------------------------------------------------------
// 0. all 4 weight transposes in ONE dispatch (1D grid, range-dispatched)
// ---------------------------------------------------------------------------
__global__ __launch_bounds__(256) void transpose_all_kernel(
        const float* __restrict__ Wi, const float* __restrict__ Wo,
        const float* __restrict__ Wx, const float* __restrict__ Wd,
        __hip_bfloat16* __restrict__ WiT, __hip_bfloat16* __restrict__ WoT,
        __hip_bfloat16* __restrict__ WxT, __hip_bfloat16* __restrict__ WdT) {
    const int t = blockIdx.x;
    const float* src; __hip_bfloat16* dst; int R, C, Cpad, nx, idx;
    if (t < 4096)      { src = Wi; dst = WiT; R = 1024; C = 4096; Cpad = 4096; nx = 128; idx = t; }
    else if (t < 6144) { src = Wo; dst = WoT; R = 2048; C = 1024; Cpad = 1024; nx = 32;  idx = t - 4096; }
    else if (t < 6400) { src = Wx; dst = WxT; R = 2048; C = 96;   Cpad = 128;  nx = 4;   idx = t - 6144; }
    else               { src = Wd; dst = WdT; R = 64;   C = 2048; Cpad = 2048; nx = 64;  idx = t - 6400; }
    __shared__ float tl[32][33];
    const int c0 = (idx % nx) * 32, r0 = (idx / nx) * 32;
    const int tx = threadIdx.x & 31, ty = threadIdx.x >> 5;   // 32 x 8
    #pragma unroll
    for (int k = 0; k < 4; k++) {
        const int r = r0 + ty + 8 * k, c = c0 + tx;
        tl[ty + 8 * k][tx] = (r < R && c < C) ? src[(size_t)r * C + c] : 0.f;
    }
    __syncthreads();
    #pragma unroll
    for (int k = 0; k < 4; k++) {
        const int c = c0 + ty + 8 * k, r = r0 + tx;
        if (c < Cpad && r < R) dst[(size_t)c * R + r] = __float2bfloat16(tl[tx][ty + 8 * k]);
    }
}

// ---------------------------------------------------------------------------
// 1. fused LayerNorm -> bf16
// ---------------------------------------------------------------------------
__global__ __launch_bounds__(256) void ln_bf16_kernel(const float* __restrict__ x,
                                                      const float* __restrict__ g,
                                                      const float* __restrict__ bta,
                                                      __hip_bfloat16* __restrict__ xn) {
    const int row = blockIdx.x;
    const int tid = threadIdx.x;
    const float4 v = ((const float4*)(x + (size_t)row * DM))[tid];
    float s  = v.x + v.y + v.z + v.w;
    float sq = v.x*v.x + v.y*v.y + v.z*v.z + v.w*v.w;
    #pragma unroll
    for (int m = 1; m < 64; m <<= 1) {
        s  += __shfl_xor(s, m);
        sq += __shfl_xor(sq, m);
    }
    __shared__ float ss[4], ssq[4];
    const int w = tid >> 6;
    if ((tid & 63) == 0) { ss[w] = s; ssq[w] = sq; }
    __syncthreads();
    s  = ss[0] + ss[1] + ss[2] + ss[3];
    sq = ssq[0] + ssq[1] + ssq[2] + ssq[3];
    const float mu  = s * (1.f / DM);
    const float var = sq * (1.f / DM) - mu * mu;
    const float rs  = rsqrtf(var + 1e-5f);
    const float4 gv = ((const float4*)g)[tid];
    const float4 bv = ((const float4*)bta)[tid];
    __hip_bfloat16* op = xn + (size_t)row * DM + tid * 4;
    op[0] = __float2bfloat16((v.x - mu) * rs * gv.x + bv.x);
    op[1] = __float2bfloat16((v.y - mu) * rs * gv.y + bv.y);
    op[2] = __float2bfloat16((v.z - mu) * rs * gv.z + bv.z);
    op[3] = __float2bfloat16((v.w - mu) * rs * gv.w + bv.w);
}

// ---------------------------------------------------------------------------
// 2. bf16 MFMA GEMM: 128x128 tile, BK=64 as two BK=32 planes, 4 waves,
//    4x4 MFMA each. XCD-aware block swizzle (lid%8 = XCD, each XCD owns
//    nby/8 contiguous row-tiles, walks them row-inner for L2 residency).
//    LDS k-chunk XOR swizzle (chunk ^= row&3, applied on the GLOBAL address
//    so global_load_lds's lane-contiguous LDS constraint is preserved):
//    8-way -> 4-way bank conflicts on fragment ds_read_b128.
//    MODE 0: Oz bf16 (cols<DI, ub), Ozb bf16 (cols>=DI, z), stride DI
//    MODE 2: O f32 = acc + Add(row-major f32), stride DM (final GEMM+residual)
//    MODE 3: Oz bf16 = softplus(acc + Add[col]) (bias), stride DI (dt)
//    MODE 4: O f32 partials [z][ROWS][128] (split-K dbc GEMM)
//    K iteration: k in [blockIdx.z*klen, +klen); row stride = Kstride.
// ---------------------------------------------------------------------------
template<int MODE>
__global__ __launch_bounds__(256) void mfma_gemm(const __hip_bfloat16* __restrict__ A,
                                                 const __hip_bfloat16* __restrict__ Bt,
                                                 float* __restrict__ O,
                                                 __hip_bfloat16* __restrict__ Oz,
                                                 __hip_bfloat16* __restrict__ Ozb,
                                                 const float* __restrict__ Add,
                                                 int Kstride, int klen) {
    __shared__ __hip_bfloat16 As[2 * 128 * 32];   // 16 KB
    __shared__ __hip_bfloat16 Bs[2 * 128 * 32];   // 16 KB
    const int tid  = threadIdx.x;
    const int lane = tid & 63;
    const int w    = tid >> 6;

    // XCD-aware swizzle: lid%8 == XCD (round-robin dispatch); each XCD gets
    // nby/8 contiguous row-tiles, iterated row-inner so its A-panel set
    // (8 x 256KB = 2MB) stays resident in its private 4MB L2.
    const int nbx = gridDim.x, nby = gridDim.y;
    const int lid = blockIdx.y * nbx + blockIdx.x;
    const int rpx = nby >> 3;
    const int xcd = lid & 7, sl = lid >> 3;
    const int by  = xcd * rpx + (sl % rpx);
    const int bx  = sl / rpx;

    const int row0 = by * 128, col0 = bx * 128;
    const int wr0 = (w >> 1) * 64, wc0 = (w & 1) * 64;

    f32x4 acc[4][4];
    #pragma unroll
    for (int i = 0; i < 4; i++)
        #pragma unroll
        for (int j = 0; j < 4; j++) acc[i][j] = f32x4{0.f, 0.f, 0.f, 0.f};

    const int fm  = lane & 15;
    const int fqi = lane >> 4;
    const int fqX = ((fqi ^ (fm & 3)) << 3);   // XOR-swizzled k-chunk offset

    const int kbeg = blockIdx.z * klen;
    for (int k0 = kbeg; k0 < kbeg + klen; k0 += 64) {
        // stage 2 planes x 128 rows x 32 k; lane-chunk c -> LDS base+c*16B
        #pragma unroll
        for (int j = 0; j < 4; j++) {
            const int c   = w * 256 + j * 64 + lane;
            const int p   = c >> 9;
            const int row = (c >> 2) & 127;
            const int q   = (c & 3) ^ (row & 3);       // XOR swizzle (global side)
            const int gk  = k0 + p * 32 + q * 8;
            __builtin_amdgcn_global_load_lds(
                (const AS1 unsigned int*)(A + (size_t)(row0 + row) * Kstride + gk),
                (AS3 unsigned int*)(As + c * 8), 16, 0, 0);
            __builtin_amdgcn_global_load_lds(
                (const AS1 unsigned int*)(Bt + (size_t)(col0 + row) * Kstride + gk),
                (AS3 unsigned int*)(Bs + c * 8), 16, 0, 0);
        }
        __syncthreads();
        #pragma unroll
        for (int half = 0; half < 2; half++) {
            bf16x8 af[4], bfr[4];
            #pragma unroll
            for (int i = 0; i < 4; i++)
                af[i] = *(const bf16x8*)&As[half * 4096 + (wr0 + i * 16 + fm) * 32 + fqX];
            #pragma unroll
            for (int j = 0; j < 4; j++)
                bfr[j] = *(const bf16x8*)&Bs[half * 4096 + (wc0 + j * 16 + fm) * 32 + fqX];
            #pragma unroll
            for (int i = 0; i < 4; i++)
                #pragma unroll
                for (int j = 0; j < 4; j++)
                    acc[i][j] = __builtin_amdgcn_mfma_f32_16x16x32_bf16(af[i], bfr[j], acc[i][j], 0, 0, 0);
        }
        __syncthreads();
    }

    // epilogue: C/D layout col=lane&15, row=(lane>>4)*4+reg  [m89/m91 verified]
    #pragma unroll
    for (int i = 0; i < 4; i++) {
        #pragma unroll
        for (int j = 0; j < 4; j++) {
            #pragma unroll
            for (int r = 0; r < 4; r++) {
                const int row = row0 + wr0 + i * 16 + (lane >> 4) * 4 + r;
                const int col = col0 + wc0 + j * 16 + fm;
                const float v = acc[i][j][r];
                if (MODE == 0) {
                    if (col0 < DI) Oz[(size_t)row * DI + col] = __float2bfloat16(v);
                    else           Ozb[(size_t)row * DI + (col - DI)] = __float2bfloat16(v);
                } else if (MODE == 2) {
                    O[(size_t)row * DM + col] = v + Add[(size_t)row * DM + col];
                } else if (MODE == 3) {
                    const float t  = v + Add[col];
                    const float sp = (t > 20.f) ? t : __logf(1.f + __expf(t));
                    Oz[(size_t)row * DI + col] = __float2bfloat16(sp);
                } else {  // MODE 4: split-K partials
                    O[((size_t)blockIdx.z * ROWS + row) * 128 + col] = v;
                }
            }
        }
    }
}

// ---------------------------------------------------------------------------
// 2b. reduce split-K partials -> dbc f32 (cols 64..95) + dbc64 bf16 (cols<64)
// ---------------------------------------------------------------------------
__global__ __launch_bounds__(256) void dbc_reduce_kernel(const float* __restrict__ pbuf,
                                                         float* __restrict__ dbc,
                                                         __hip_bfloat16* __restrict__ dbc64) {
    const size_t gid = (size_t)blockIdx.x * 256 + threadIdx.x;   // ROWS*128
    const int    col = gid & 127;
    const size_t row = gid >> 7;
    float sum = 0.f;
    #pragma unroll
    for (int sp = 0; sp < 4; sp++)
        sum += pbuf[((size_t)sp * ROWS + row) * 128 + col];
    if (col < DTR)                   dbc64[row * DTR + col] = __float2bfloat16(sum);
    else if (col < DTR + 2 * DST)    dbc[row * 128 + col] = sum;
}

// ---------------------------------------------------------------------------
// 3. depthwise causal conv(4) + bias + SiLU.  ub bf16 [rows][DI] -> uc bf16
// ---------------------------------------------------------------------------
__global__ __launch_bounds__(256) void conv_silu_kernel(const __hip_bfloat16* __restrict__ u,
                                                        const float* __restrict__ cw,
                                                        const float* __restrict__ cb,
                                                        __hip_bfloat16* __restrict__ uc) {
    const int d  = blockIdx.x * 256 + threadIdx.x;
    const int b  = blockIdx.z;
    const int l0 = blockIdx.y * 16;
    const float w0 = cw[d * 4 + 0], w1 = cw[d * 4 + 1];
    const float w2 = cw[d * 4 + 2], w3 = cw[d * 4 + 3];
    const float bias = cb[d];
    const __hip_bfloat16* up = u + (size_t)(b * LL) * DI + d;
    float x0 = (l0 - 3 >= 0) ? __bfloat162float(up[(size_t)(l0 - 3) * DI]) : 0.f;
    float x1 = (l0 - 2 >= 0) ? __bfloat162float(up[(size_t)(l0 - 2) * DI]) : 0.f;
    float x2 = (l0 - 1 >= 0) ? __bfloat162float(up[(size_t)(l0 - 1) * DI]) : 0.f;
    __hip_bfloat16* op = uc + (size_t)(b * LL + l0) * DI + d;
    #pragma unroll
    for (int i = 0; i < 16; i++) {
        const float x3 = __bfloat162float(up[(size_t)(l0 + i) * DI]);
        const float v  = bias + w0 * x0 + w1 * x1 + w2 * x2 + w3 * x3;
        const float sig = __builtin_amdgcn_rcpf(1.f + __expf(-v));
        op[(size_t)i * DI] = __float2bfloat16(v * sig);
        x0 = x1; x1 = x2; x2 = x3;
    }
}

// ---------------------------------------------------------------------------
// 6a. scan pass 1 (thread-per-channel): h[16] in registers, B from LDS.
// ---------------------------------------------------------------------------
__global__ __launch_bounds__(256) void scan_pass1_kernel(const __hip_bfloat16* __restrict__ dtb,
                                                         const __hip_bfloat16* __restrict__ uc,
                                                         const float* __restrict__ dbc,
                                                         const float* __restrict__ A_log,
                                                         float* __restrict__ hbuf,
                                                         float* __restrict__ Pbuf) {
    __shared__ float Bsh[CHUNK][16];      // 4 KB
    const int tid = threadIdx.x;
    const int d   = blockIdx.x * 256 + tid;
    const int c   = blockIdx.y;
    const int b   = blockIdx.z;
    const size_t row0 = (size_t)b * LL + (size_t)c * CHUNK;

    {
        const int r = tid >> 2, j4 = (tid & 3) * 4;
        *(float4*)&Bsh[r][j4] = *(const float4*)(dbc + (row0 + r) * 128 + DTR + j4);
    }
    float a[DST];
    #pragma unroll
    for (int q = 0; q < 4; q++) {
        const float4 t = *(const float4*)(A_log + (size_t)d * DST + q * 4);
        a[q * 4 + 0] = -__expf(t.x); a[q * 4 + 1] = -__expf(t.y);
        a[q * 4 + 2] = -__expf(t.z); a[q * 4 + 3] = -__expf(t.w);
    }
    __syncthreads();

    const __hip_bfloat16* dtp = dtb + row0 * DI + d;
    const __hip_bfloat16* ucp = uc + row0 * DI + d;

    float h[DST];
    #pragma unroll
    for (int s = 0; s < DST; s++) h[s] = 0.f;
    float sdt = 0.f;
    float dtv = __bfloat162float(dtp[0]), ucv = __bfloat162float(ucp[0]);
    for (int l = 0; l < CHUNK; l++) {
        const int ln = (l + 1 < CHUNK) ? (l + 1) : l;
        const float dtn = __bfloat162float(dtp[(size_t)ln * DI]);
        const float ucn = __bfloat162float(ucp[(size_t)ln * DI]);
        const float dtu = dtv * ucv;
        sdt += dtv;
        #pragma unroll
        for (int s = 0; s < DST; s++) {
            const float dA = __expf(dtv * a[s]);
            h[s] = fmaf(h[s], dA, dtu * Bsh[l][s]);
        }
        dtv = dtn; ucv = ucn;
    }
    float* hp = hbuf + (((size_t)b * NC + c) * DI + d) * DST;
    float* pp = Pbuf + (((size_t)b * NC + c) * DI + d) * DST;
    #pragma unroll
    for (int q = 0; q < 4; q++) {
        *(float4*)&hp[q * 4] = float4{h[q*4+0], h[q*4+1], h[q*4+2], h[q*4+3]};
        *(float4*)&pp[q * 4] = float4{__expf(sdt * a[q*4+0]), __expf(sdt * a[q*4+1]),
                                      __expf(sdt * a[q*4+2]), __expf(sdt * a[q*4+3])};
    }
}

// ---------------------------------------------------------------------------
// 6b. scan combine: rewrite hbuf[c] := h_in for chunk c
// ---------------------------------------------------------------------------
__global__ __launch_bounds__(256) void scan_combine_kernel(float* __restrict__ hbuf,
                                                           const float* __restrict__ Pbuf) {
    const size_t gid  = (size_t)blockIdx.x * 256 + threadIdx.x;
    const size_t b    = gid >> 15;             // DI*DST = 32768
    const size_t d16s = gid & 32767;
    float H = 0.f;
    #pragma unroll
    for (int c = 0; c < NC; c++) {
        const size_t idx = (b * NC + c) * (DI * DST) + d16s;
        const float hc = hbuf[idx];
        const float Pc = Pbuf[idx];
        hbuf[idx] = H;
        H = hc + Pc * H;
    }
}

// ---------------------------------------------------------------------------
// 6c. scan pass 3 (thread-per-channel): y + D-skip + SiLU(z) gate, in place.
// ---------------------------------------------------------------------------
__global__ __launch_bounds__(256) void scan_pass3_kernel(const __hip_bfloat16* __restrict__ dtb,
                                                         __hip_bfloat16* uc,
                                                         const __hip_bfloat16* __restrict__ z,
                                                         const float* __restrict__ dbc,
                                                         const float* __restrict__ A_log,
                                                         const float* __restrict__ Dskip,
                                                         const float* __restrict__ hbuf) {
    __shared__ float BC[CHUNK][32];       // 8 KB: [0:16)=B, [16:32)=C
    const int tid = threadIdx.x;
    const int d   = blockIdx.x * 256 + tid;
    const int c   = blockIdx.y;
    const int b   = blockIdx.z;
    const size_t row0 = (size_t)b * LL + (size_t)c * CHUNK;

    #pragma unroll
    for (int i = 0; i < 2; i++) {
        const int idx = i * 256 + tid;
        const int r = idx >> 3, j4 = (idx & 7) * 4;
        *(float4*)&BC[r][j4] = *(const float4*)(dbc + (row0 + r) * 128 + DTR + j4);
    }
    float a[DST];
    #pragma unroll
    for (int q = 0; q < 4; q++) {
        const float4 t = *(const float4*)(A_log + (size_t)d * DST + q * 4);
        a[q * 4 + 0] = -__expf(t.x); a[q * 4 + 1] = -__expf(t.y);
        a[q * 4 + 2] = -__expf(t.z); a[q * 4 + 3] = -__expf(t.w);
    }
    const float dsk = Dskip[d];
    __syncthreads();

    const __hip_bfloat16* dtp = dtb + row0 * DI + d;
    __hip_bfloat16* ucp = uc + row0 * DI + d;
    const __hip_bfloat16* zp = z + row0 * DI + d;

    float h[DST];
    {
        const float* hp = hbuf + (((size_t)b * NC + c) * DI + d) * DST;
        #pragma unroll
        for (int q = 0; q < 4; q++) {
            const float4 t = *(const float4*)&hp[q * 4];
            h[q*4+0] = t.x; h[q*4+1] = t.y; h[q*4+2] = t.z; h[q*4+3] = t.w;
        }
    }
    float dtv = __bfloat162float(dtp[0]);
    float ucv = __bfloat162float(ucp[0]);
    float zv  = __bfloat162float(zp[0]);
    for (int l = 0; l < CHUNK; l++) {
        const int ln = (l + 1 < CHUNK) ? (l + 1) : l;
        const float dtn = __bfloat162float(dtp[(size_t)ln * DI]);
        const float ucn = __bfloat162float(ucp[(size_t)ln * DI]);
        const float zn  = __bfloat162float(zp[(size_t)ln * DI]);
        const float dtu = dtv * ucv;
        float y = 0.f;
        #pragma unroll
        for (int s = 0; s < DST; s++) {
            const float dA = __expf(dtv * a[s]);
            h[s] = fmaf(h[s], dA, dtu * BC[l][s]);
            y = fmaf(h[s], BC[l][16 + s], y);
        }
        const float yt  = fmaf(ucv, dsk, y);
        const float sig = __builtin_amdgcn_rcpf(1.f + __expf(-zv));
        ucp[(size_t)l * DI] = __float2bfloat16(yt * (zv * sig));
        dtv = dtn; ucv = ucn; zv = zn;
    }
}

// ---------------------------------------------------------------------------
extern "C" void kernel_launch(void* const* d_in, const int* in_sizes, int n_in,
                              void* d_out, int out_size, void* d_ws, size_t ws_size,
                              hipStream_t stream) {
    const float* x      = (const float*)d_in[0];
    const float* ln_g   = (const float*)d_in[1];
    const float* ln_b   = (const float*)d_in[2];
    const float* W_in   = (const float*)d_in[3];
    const float* conv_w = (const float*)d_in[4];
    const float* conv_b = (const float*)d_in[5];
    const float* W_x    = (const float*)d_in[6];
    const float* W_dt   = (const float*)d_in[7];
    const float* b_dt   = (const float*)d_in[8];
    const float* A_log  = (const float*)d_in[9];
    const float* Dskip  = (const float*)d_in[10];
    const float* W_out  = (const float*)d_in[11];
    float* out = (float*)d_out;

    // workspace layout (bytes), total ~179 MB (proven budget: 195 MB)
    const size_t MB = 1024ull * 1024ull;
    char* wsb = (char*)d_ws;
    __hip_bfloat16* ub    = (__hip_bfloat16*)(wsb);            // 32 MB: u -> dt
    __hip_bfloat16* z     = (__hip_bfloat16*)(wsb + 32 * MB);  // 32 MB
    __hip_bfloat16* uc    = (__hip_bfloat16*)(wsb + 64 * MB);  // 32 MB: uc -> yg
    __hip_bfloat16* xn    = (__hip_bfloat16*)(wsb + 96 * MB);  // 16 MB
    __hip_bfloat16* WinT  = (__hip_bfloat16*)(wsb + 112 * MB); // 8 MB
    __hip_bfloat16* WoutT = (__hip_bfloat16*)(wsb + 120 * MB); // 4 MB
    __hip_bfloat16* WxT   = (__hip_bfloat16*)(wsb + 124 * MB); // 0.5 MB
    float*          dbc   = (float*)(wsb + 125 * MB);          // 4 MB [8192][128]
    float*          hbuf  = (float*)(wsb + 129 * MB);          // 16 MB
    float*          Pbuf  = (float*)(wsb + 145 * MB);          // 16 MB
    __hip_bfloat16* dbc64 = (__hip_bfloat16*)(wsb + 161 * MB); // 1 MB [8192][64]
    __hip_bfloat16* WdtT  = (__hip_bfloat16*)(wsb + 162 * MB); // 0.25 MB [2048][64]
    float*          pbuf  = (float*)(wsb + 163 * MB);          // 16 MB [4][8192][128]
    __hip_bfloat16* dtb   = ub;                                // reuse (u dead after conv)

    transpose_all_kernel<<<6528, 256, 0, stream>>>(W_in, W_out, W_x, W_dt,
                                                   WinT, WoutT, WxT, WdtT);
    ln_bf16_kernel<<<ROWS, 256, 0, stream>>>(x, ln_g, ln_b, xn);
    mfma_gemm<0><<<dim3(32, 64), 256, 0, stream>>>(
        xn, WinT, nullptr, ub, z, nullptr, DM, DM);
    conv_silu_kernel<<<dim3(DI / 256, LL / 16, BB), 256, 0, stream>>>(ub, conv_w, conv_b, uc);
    mfma_gemm<4><<<dim3(1, 64, 4), 256, 0, stream>>>(
        uc, WxT, pbuf, nullptr, nullptr, nullptr, DI, DI / 4);
    dbc_reduce_kernel<<<(ROWS * 128) / 256, 256, 0, stream>>>(pbuf, dbc, dbc64);
    mfma_gemm<3><<<dim3(DI / 128, ROWS / 128), 256, 0, stream>>>(
        dbc64, WdtT, nullptr, dtb, nullptr, b_dt, DTR, DTR);
    scan_pass1_kernel<<<dim3(DI / 256, NC, BB), 256, 0, stream>>>(dtb, uc, dbc, A_log, hbuf, Pbuf);
    scan_combine_kernel<<<(BB * DI * DST) / 256, 256, 0, stream>>>(hbuf, Pbuf);
    scan_pass3_kernel<<<dim3(DI / 256, NC, BB), 256, 0, stream>>>(dtb, uc, z, dbc, A_log, Dskip, hbuf);
    mfma_gemm<2><<<dim3(DM / 128, ROWS / 128), 256, 0, stream>>>(
        uc, WoutT, out, nullptr, nullptr, x, DI, DI);
}